// Round 1
// baseline (94.632 us; speedup 1.0000x reference)
//
#include <hip/hip_runtime.h>
#include <math.h>

#define BB 2
#define NN 512
#define IND 64
#define HH 8
#define DD 8
#define CC 64          // H*D
#define JCHUNK 64
#define NWAVES 4       // 256 threads / wave64

// ---------------- Kernel 1: Q,K,V projections ----------------
// Q[b,i,c] = sum_k h[b,i,k] * WQ[c,k];  K pre-scaled by D^-0.5
__global__ __launch_bounds__(64)
void qkv_kernel(const float* __restrict__ h,
                const float* __restrict__ WQ,
                const float* __restrict__ WK,
                const float* __restrict__ WV,
                float* __restrict__ Qw,
                float* __restrict__ Kw,
                float* __restrict__ Vw) {
    int bi = blockIdx.x;          // b*N + i
    int c  = threadIdx.x;         // 0..63
    __shared__ float hrow[IND];
    hrow[c] = h[bi * IND + c];
    __syncthreads();
    float aq = 0.f, ak = 0.f, av = 0.f;
#pragma unroll
    for (int k = 0; k < IND; ++k) {
        float hv = hrow[k];
        aq += hv * WQ[c * IND + k];
        ak += hv * WK[c * IND + k];
        av += hv * WV[c * IND + k];
    }
    Qw[bi * CC + c] = aq;
    Kw[bi * CC + c] = ak * 0.35355339059327376f;  // 8^-0.5
    Vw[bi * CC + c] = av;
}

// ---------------- Kernel 2: fused masked softmax-attention ----------------
// One block per (b,i). 256 threads = 4 j-phases x 64 channels.
__global__ __launch_bounds__(256)
void attn_kernel(const float* __restrict__ e_att,
                 const float* __restrict__ e_value,
                 const int*   __restrict__ mask,
                 const float* __restrict__ Qw,
                 const float* __restrict__ Kw,
                 const float* __restrict__ Vw,
                 float* __restrict__ out) {
    int bi  = blockIdx.x;          // b*N + i
    int b   = bi >> 9;             // / N
    int tid = threadIdx.x;
    int jt  = tid >> 6;            // wave id 0..3 (j phase)
    int c   = tid & 63;            // channel
    int hh  = c >> 3;              // head

    __shared__ float Qrow[CC];
    __shared__ float qk_s[JCHUNK * HH];      // [j_loc][h]
    __shared__ float m_s[NWAVES][CC];
    __shared__ float l_s[NWAVES][CC];
    __shared__ float a_s[NWAVES][CC];

    if (tid < CC) Qrow[tid] = Qw[bi * CC + tid];

    const float* Kb     = Kw + (size_t)b * NN * CC;
    const float* Vb     = Vw + (size_t)b * NN * CC;
    const float* ea_row = e_att   + (size_t)bi * NN * CC;
    const float* ev_row = e_value + (size_t)bi * NN * CC;
    const int*   mrow   = mask    + (size_t)bi * NN;   // b*N*N + i*N

    float m = -INFINITY, l = 0.f, acc = 0.f;

    for (int j0 = 0; j0 < NN; j0 += JCHUNK) {
        __syncthreads();  // qk_s (re)write safe; also covers Qrow on first iter
        // cooperative qk: 512 entries e = j_loc*8 + h, 2 per thread
#pragma unroll
        for (int r = 0; r < 2; ++r) {
            int e  = tid + r * 256;
            int jl = e >> 3;
            int eh = e & 7;
            const float* krow = Kb + (size_t)(j0 + jl) * CC + eh * 8;
            float s = 0.f;
#pragma unroll
            for (int d = 0; d < 8; ++d) s += Qrow[eh * 8 + d] * krow[d];
            qk_s[e] = s;
        }
        __syncthreads();

        // stream 64 j's: 16 iterations of 4 parallel j's
        for (int t = 0; t < JCHUNK / NWAVES; ++t) {
            int jl = t * NWAVES + jt;
            int j  = j0 + jl;
            if (mrow[j]) {                         // wave-uniform branch
                float ea = ea_row[(size_t)j * CC + c];
                float ev = ev_row[(size_t)j * CC + c];
                float v  = Vb[(size_t)j * CC + c];
                float s  = qk_s[jl * HH + hh] + ea;
                float mn = fmaxf(m, s);
                float sc = __expf(m - mn);
                float p  = __expf(s - mn);
                l   = l * sc + p;
                acc = acc * sc + p * (v + ev);
                m   = mn;
            }
        }
    }

    m_s[jt][c] = m; l_s[jt][c] = l; a_s[jt][c] = acc;
    __syncthreads();

    if (jt == 0) {
        float M = -INFINITY;
#pragma unroll
        for (int k = 0; k < NWAVES; ++k) M = fmaxf(M, m_s[k][c]);
        float L = 0.f, A = 0.f;
#pragma unroll
        for (int k = 0; k < NWAVES; ++k) {
            float lk = l_s[k][c];
            if (lk > 0.f) {
                float sc = __expf(m_s[k][c] - M);
                L += lk * sc;
                A += a_s[k][c] * sc;
            }
        }
        out[bi * CC + c] = (L > 0.f) ? (A / L) : 0.f;
    }
}

extern "C" void kernel_launch(void* const* d_in, const int* in_sizes, int n_in,
                              void* d_out, int out_size, void* d_ws, size_t ws_size,
                              hipStream_t stream) {
    const float* h       = (const float*)d_in[0];
    const float* e_att   = (const float*)d_in[1];
    const float* e_value = (const float*)d_in[2];
    const int*   mask    = (const int*)  d_in[3];
    const float* WQ      = (const float*)d_in[4];
    const float* WK      = (const float*)d_in[5];
    const float* WV      = (const float*)d_in[6];
    float* out = (float*)d_out;

    // workspace: Qw | Kw | Vw, each B*N*C floats
    float* Qw = (float*)d_ws;
    float* Kw = Qw + (size_t)BB * NN * CC;
    float* Vw = Kw + (size_t)BB * NN * CC;

    qkv_kernel<<<BB * NN, 64, 0, stream>>>(h, WQ, WK, WV, Qw, Kw, Vw);
    attn_kernel<<<BB * NN, 256, 0, stream>>>(e_att, e_value, mask, Qw, Kw, Vw, out);
}

// Round 2
// 57.392 us; speedup vs baseline: 1.6489x; 1.6489x over previous
//
#include <hip/hip_runtime.h>
#include <math.h>

#define BB 2
#define NN 512
#define IND 64
#define HH 8
#define DD 8
#define CC 64          // H*D channels
#define QUADS 16       // channel quads per j (CC/4)
#define JGROUPS 16     // parallel j slots per block (256 threads / 16 quads)
#define JITERS (NN / JGROUPS)   // 32 j-iterations per thread

// ---------------- Kernel 1: Q,K,V projections ----------------
__global__ __launch_bounds__(64)
void qkv_kernel(const float* __restrict__ h,
                const float* __restrict__ WQ,
                const float* __restrict__ WK,
                const float* __restrict__ WV,
                float* __restrict__ Qw,
                float* __restrict__ Kw,
                float* __restrict__ Vw) {
    int bi = blockIdx.x;          // b*N + i
    int c  = threadIdx.x;         // 0..63
    __shared__ float hrow[IND];
    hrow[c] = h[bi * IND + c];
    __syncthreads();
    float aq = 0.f, ak = 0.f, av = 0.f;
#pragma unroll
    for (int k = 0; k < IND; ++k) {
        float hv = hrow[k];
        aq += hv * WQ[c * IND + k];
        ak += hv * WK[c * IND + k];
        av += hv * WV[c * IND + k];
    }
    Qw[bi * CC + c] = aq;
    Kw[bi * CC + c] = ak * 0.35355339059327376f;  // 8^-0.5
    Vw[bi * CC + c] = av;
}

// ---------------- Kernel 2: fused masked softmax-attention ----------------
// One block per (b,i). 256 threads: q = tid&15 (channel quad, float4),
// jg = tid>>4 (16 parallel j slots). Branchless online softmax.
__global__ __launch_bounds__(256)
void attn_kernel(const float* __restrict__ e_att,
                 const float* __restrict__ e_value,
                 const int*   __restrict__ mask,
                 const float* __restrict__ Qw,
                 const float* __restrict__ Kw,
                 const float* __restrict__ Vw,
                 float* __restrict__ out) {
    int bi  = blockIdx.x;          // b*N + i
    int b   = bi >> 9;             // / N
    int tid = threadIdx.x;
    int q   = tid & 15;            // channel quad: channels 4q..4q+3
    int jg  = tid >> 4;            // j slot 0..15
    int hh  = q >> 1;              // head of this quad (8 ch/head, 4 ch/quad)

    __shared__ float Qrow[CC];
    __shared__ float qk_s[NN * HH];          // [j][h], 16 KB
    __shared__ float maskf[NN];              // 0/1 floats, 2 KB
    __shared__ float4 ms4[JGROUPS][QUADS];   // partial m, 4 KB
    __shared__ float4 ls4[JGROUPS][QUADS];   // partial l
    __shared__ float4 as4[JGROUPS][QUADS];   // partial acc

    if (tid < CC) Qrow[tid] = Qw[bi * CC + tid];
    {
        const int* mrow = mask + (size_t)bi * NN;
        maskf[tid]       = mrow[tid]       ? 1.f : 0.f;
        maskf[tid + 256] = mrow[tid + 256] ? 1.f : 0.f;
    }
    __syncthreads();

    const float* Kb = Kw + (size_t)b * NN * CC;
    const float* Vb = Vw + (size_t)b * NN * CC;

    // Precompute all qk[j][h] = sum_d Qrow[h*8+d] * Kb[j*64 + h*8 + d]
#pragma unroll
    for (int e = tid; e < NN * HH; e += 256) {
        int j = e >> 3, h = e & 7;
        const float* kr = Kb + (size_t)j * CC + h * 8;
        float s = 0.f;
#pragma unroll
        for (int d = 0; d < 8; ++d) s += Qrow[h * 8 + d] * kr[d];
        qk_s[e] = s;
    }
    __syncthreads();

    const float* ea_row = e_att   + (size_t)bi * NN * CC + q * 4;
    const float* ev_row = e_value + (size_t)bi * NN * CC + q * 4;
    const float* v_col  = Vb + q * 4;

    float m[4], l[4], a[4];
#pragma unroll
    for (int cc = 0; cc < 4; ++cc) { m[cc] = -1e30f; l[cc] = 0.f; a[cc] = 0.f; }

#pragma unroll 4
    for (int it = 0; it < JITERS; ++it) {
        int j = it * JGROUPS + jg;
        float ea[4], ev[4], vv[4];
        *(float4*)ea = *(const float4*)(ea_row + (size_t)j * CC);
        *(float4*)ev = *(const float4*)(ev_row + (size_t)j * CC);
        *(float4*)vv = *(const float4*)(v_col  + (size_t)j * CC);
        float qk  = qk_s[j * HH + hh];
        float msk = maskf[j];
#pragma unroll
        for (int cc = 0; cc < 4; ++cc) {
            float s  = qk + ea[cc];
            float sm = (msk != 0.f) ? s : -1e30f;
            float mn = fmaxf(m[cc], sm);
            float sc = __expf(m[cc] - mn);
            float p  = msk * __expf(sm - mn);
            l[cc] = l[cc] * sc + p;
            a[cc] = a[cc] * sc + p * (vv[cc] + ev[cc]);
            m[cc] = mn;
        }
    }

    ms4[jg][q] = make_float4(m[0], m[1], m[2], m[3]);
    ls4[jg][q] = make_float4(l[0], l[1], l[2], l[3]);
    as4[jg][q] = make_float4(a[0], a[1], a[2], a[3]);
    __syncthreads();

    // Combine 16 partials per channel; threads 0..63 each own one channel.
    if (tid < CC) {
        int cq = tid >> 2, sub = tid & 3;
        float M = -1e30f;
#pragma unroll
        for (int k = 0; k < JGROUPS; ++k)
            M = fmaxf(M, ((const float*)&ms4[k][cq])[sub]);
        float L = 0.f, A = 0.f;
#pragma unroll
        for (int k = 0; k < JGROUPS; ++k) {
            float sc = __expf(((const float*)&ms4[k][cq])[sub] - M);
            L += ((const float*)&ls4[k][cq])[sub] * sc;
            A += ((const float*)&as4[k][cq])[sub] * sc;
        }
        out[(size_t)bi * CC + tid] = (L > 0.f) ? (A / L) : 0.f;
    }
}

extern "C" void kernel_launch(void* const* d_in, const int* in_sizes, int n_in,
                              void* d_out, int out_size, void* d_ws, size_t ws_size,
                              hipStream_t stream) {
    const float* h       = (const float*)d_in[0];
    const float* e_att   = (const float*)d_in[1];
    const float* e_value = (const float*)d_in[2];
    const int*   mask    = (const int*)  d_in[3];
    const float* WQ      = (const float*)d_in[4];
    const float* WK      = (const float*)d_in[5];
    const float* WV      = (const float*)d_in[6];
    float* out = (float*)d_out;

    float* Qw = (float*)d_ws;
    float* Kw = Qw + (size_t)BB * NN * CC;
    float* Vw = Kw + (size_t)BB * NN * CC;

    qkv_kernel<<<BB * NN, 64, 0, stream>>>(h, WQ, WK, WV, Qw, Kw, Vw);
    attn_kernel<<<BB * NN, 256, 0, stream>>>(e_att, e_value, mask, Qw, Kw, Vw, out);
}